// Round 9
// baseline (1962.786 us; speedup 1.0000x reference)
//
#include <hip/hip_runtime.h>
#include <hip/hip_bf16.h>
#include <math.h>

#define B 4
#define S 2048
#define H 768
#define V 32000
#define HID 100
#define G4 400   // 4*HID
#define M_TOT (B*S)
#define PD 2     // xproj prefetch depth (steps)

typedef _Float16 half2_t __attribute__((ext_vector_type(2)));
typedef _Float16 half8_t __attribute__((ext_vector_type(8)));

__device__ __forceinline__ float fdot2_(half2_t a, half2_t b, float c) {
#if __has_builtin(__builtin_amdgcn_fdot2)
  return __builtin_amdgcn_fdot2(a, b, c, false);
#else
  return c + (float)a[0] * (float)b[0] + (float)a[1] * (float)b[1];
#endif
}

__device__ __forceinline__ float sigmoidf_(float x) {
  return 1.0f / (1.0f + __expf(-x));
}

// Raw workgroup barrier: orders LDS (lgkmcnt drain) but does NOT drain vmcnt,
// so global prefetch loads stay in flight across steps.
__device__ __forceinline__ void lds_barrier_() {
  asm volatile("s_waitcnt lgkmcnt(0)" ::: "memory");
  __builtin_amdgcn_s_barrier();
  asm volatile("" ::: "memory");
}

// ---------------- Kernel 1: surprisal (online softmax + gather) --------------
__global__ __launch_bounds__(256) void surprisal_kernel(
    const float* __restrict__ logits, const int* __restrict__ ids,
    const float* __restrict__ mask, float* __restrict__ surp) {
  int row = blockIdx.x;
  const float* x = logits + (size_t)row * V;
  int tid = threadIdx.x;
  float m = -INFINITY, s = 0.0f;
  const float4* x4 = (const float4*)x;
  for (int i = tid; i < V / 4; i += 256) {
    float4 v = x4[i];
    float mv = fmaxf(fmaxf(v.x, v.y), fmaxf(v.z, v.w));
    if (mv > m) { s *= __expf(m - mv); m = mv; }
    s += __expf(v.x - m) + __expf(v.y - m) + __expf(v.z - m) + __expf(v.w - m);
  }
  #pragma unroll
  for (int off = 32; off > 0; off >>= 1) {
    float mo = __shfl_xor(m, off);
    float so = __shfl_xor(s, off);
    float mn = fmaxf(m, mo);
    s = s * __expf(m - mn) + so * __expf(mo - mn);
    m = mn;
  }
  __shared__ float sm[4], ss[4];
  int wid = tid >> 6, lane = tid & 63;
  if (lane == 0) { sm[wid] = m; ss[wid] = s; }
  __syncthreads();
  if (tid == 0) {
    float M = sm[0], Ssum = ss[0];
    #pragma unroll
    for (int w = 1; w < 4; ++w) {
      float mo = sm[w], so = ss[w];
      float mn = fmaxf(M, mo);
      Ssum = Ssum * __expf(M - mn) + so * __expf(mo - mn);
      M = mn;
    }
    float xid = x[ids[row]];
    surp[row] = (M + __logf(Ssum) - xid) * 1.4426950408889634f * mask[row];
  }
}

// ---------------- Kernel 2: x_proj (PERMUTED: col 4*unit + bitrev2(gate)) ----
// gate g in {i=0,f=1,g=2,o=3} -> slot {0,2,1,3}; so thread q of the LSTM
// (even q: unit q/2 gates (i,g); odd q: gates (f,o)) loads one float2 at 2q.
#define BM 64
#define BN 64
#define BK 32

__global__ __launch_bounds__(256) void xproj_kernel(
    const float* __restrict__ A,     // hidden_states [M,768]
    const float* __restrict__ surp,  // [M]
    const float* __restrict__ W,     // W_ih [400,769]
    const float* __restrict__ b_ih, const float* __restrict__ b_hh,
    float* __restrict__ xproj) {     // [M,400] permuted
  __shared__ float As[BK][BM];
  __shared__ float Bs[BK][BN];
  int tid = threadIdx.x;
  int m0 = blockIdx.x * BM;
  int n0 = blockIdx.y * BN;
  int tx = tid & 15, ty = tid >> 4;
  float acc[4][4] = {};
  for (int k0 = 0; k0 < H; k0 += BK) {
    #pragma unroll
    for (int l = 0; l < 2; ++l) {
      int idx = tid + l * 256;        // 0..511
      int row = idx >> 3;
      int kq = idx & 7;
      float4 v = *(const float4*)&A[(size_t)(m0 + row) * H + k0 + kq * 4];
      As[kq * 4 + 0][row] = v.x;
      As[kq * 4 + 1][row] = v.y;
      As[kq * 4 + 2][row] = v.z;
      As[kq * 4 + 3][row] = v.w;
    }
    #pragma unroll
    for (int l = 0; l < 8; ++l) {
      int idx = tid + l * 256;        // 0..2047
      int n = idx >> 5;
      int kk = idx & 31;
      int gn = n0 + n;
      Bs[kk][n] = (gn < G4) ? W[(size_t)gn * (H + 1) + k0 + kk] : 0.0f;
    }
    __syncthreads();
    #pragma unroll
    for (int k = 0; k < BK; ++k) {
      float4 a = *(const float4*)&As[k][ty * 4];
      float4 bq = *(const float4*)&Bs[k][tx * 4];
      float av[4] = {a.x, a.y, a.z, a.w};
      float bv[4] = {bq.x, bq.y, bq.z, bq.w};
      #pragma unroll
      for (int i = 0; i < 4; ++i)
        #pragma unroll
        for (int j = 0; j < 4; ++j)
          acc[i][j] += av[i] * bv[j];
    }
    __syncthreads();
  }
  #pragma unroll
  for (int i = 0; i < 4; ++i) {
    int gm = m0 + ty * 4 + i;
    float sv = surp[gm];
    #pragma unroll
    for (int j = 0; j < 4; ++j) {
      int gn = n0 + tx * 4 + j;   // gate-row index r = g*100 + k
      if (gn < G4) {
        float val = acc[i][j] + sv * W[(size_t)gn * (H + 1) + H] + b_ih[gn] + b_hh[gn];
        int g = gn / HID, k = gn % HID;
        int pn = 4 * k + (((g & 1) << 1) | (g >> 1));   // bitrev2(g)
        xproj[(size_t)gm * G4 + pn] = val;
      }
    }
  }
}

// ---------------- Kernel 3: LSTM scan + classifier ---------------------------
// TWO BATCH GROUPS PER BLOCK (512 thr): group = tid>>8 handles batch
// 2*blockIdx+group; each group is the round-8 pair structure (thread q<200
// owns two gate rows of unit q/2: even q -> (i,g), odd q -> (f,o); weights as
// half2 in regs; 104 v_dot2 per step; local activations; two shfl_xor(1);
// one raw barrier/step; double-buffered h per group). Wave->SIMD round-robin
// puts one wave of EACH group on every SIMD, so group A's deterministic
// stalls (LDS return, dot-chain tail, transcendental chains) are filled by
// group B's issue. xproj pre-permuted -> coalesced float2/thread/step.
#define NH2 52          // 50 half2 + 2 zero-pad -> 13 x b128
__global__ __launch_bounds__(512, 2) void lstm_kernel(
    const float* __restrict__ xproj,  // [B,S,400] permuted cols
    const float* __restrict__ W_hh,   // [400,100]
    const float* __restrict__ sent,   // [B,3]
    const float* __restrict__ cls_W,  // [3,103]
    const float* __restrict__ cls_b,  // [3]
    float* __restrict__ out) {        // [B,3]
  int grp = threadIdx.x >> 8;          // 0 or 1
  int tid = threadIdx.x & 255;         // index within group
  int b = blockIdx.x * 2 + grp;
  __shared__ __align__(16) _Float16 hb0[2][2 * NH2];
  __shared__ __align__(16) _Float16 hb1[2][2 * NH2];

  bool active = tid < 200;
  int q = active ? tid : 199;          // clamp for uniform control flow
  int k = q >> 1;
  bool odd = (q & 1) != 0;
  int rA = odd ? (HID + k) : k;                  // f : i
  int rB = odd ? (3 * HID + k) : (2 * HID + k);  // o : g

  half2_t wA[NH2], wB[NH2];
  {
    const float* pA = W_hh + (size_t)rA * HID;
    const float* pB = W_hh + (size_t)rB * HID;
    #pragma unroll
    for (int j = 0; j < 50; ++j) {
      wA[j] = half2_t{(_Float16)pA[2 * j], (_Float16)pA[2 * j + 1]};
      wB[j] = half2_t{(_Float16)pB[2 * j], (_Float16)pB[2 * j + 1]};
    }
    #pragma unroll
    for (int j = 50; j < NH2; ++j) { wA[j] = half2_t{0, 0}; wB[j] = half2_t{0, 0}; }
  }

  float c_reg = 0.0f;
  if (tid < 2 * NH2) { hb0[grp][tid] = (_Float16)0; hb1[grp][tid] = (_Float16)0; }
  __syncthreads();

  const float* xp = xproj + (size_t)b * S * G4;
  float2 xr[PD];
  #pragma unroll
  for (int d = 0; d < PD; ++d)
    xr[d] = ((const float2*)(xp + (size_t)d * G4))[q];

  #pragma unroll 2
  for (int t = 0; t < S; ++t) {
    int slot = t & (PD - 1);                       // static under unroll 2
    const half8_t* hr = (t & 1) ? (const half8_t*)hb0[grp] : (const half8_t*)hb1[grp];
    _Float16* hw = (t & 1) ? hb1[grp] : hb0[grp];

    float2 xv = xr[slot];
    // refill ring slot early (independent; stays in flight across barriers)
    {
      int tp = (t + PD < S) ? (t + PD) : (S - 1);
      xr[slot] = ((const float2*)(xp + (size_t)tp * G4))[q];
    }

    float a0 = 0.f, a1 = 0.f, b0 = 0.f, b1 = 0.f;
    #pragma unroll
    for (int j = 0; j < 13; ++j) {
      half8_t hv = hr[j];                          // uniform addr -> broadcast
      half2_t h0 = {hv[0], hv[1]}, h1 = {hv[2], hv[3]};
      half2_t h2 = {hv[4], hv[5]}, h3 = {hv[6], hv[7]};
      a0 = fdot2_(wA[4 * j + 0], h0, a0);
      b0 = fdot2_(wB[4 * j + 0], h0, b0);
      a1 = fdot2_(wA[4 * j + 1], h1, a1);
      b1 = fdot2_(wB[4 * j + 1], h1, b1);
      a0 = fdot2_(wA[4 * j + 2], h2, a0);
      b0 = fdot2_(wB[4 * j + 2], h2, b0);
      a1 = fdot2_(wA[4 * j + 3], h3, a1);
      b1 = fdot2_(wB[4 * j + 3], h3, b1);
    }
    float aA = a0 + a1 + xv.x;   // even: i_pre ; odd: f_pre
    float aB = b0 + b1 + xv.y;   // even: g_pre ; odd: o_pre

    // local activations (uniform instruction stream, per-lane selects):
    float vA = sigmoidf_(aA);                       // i or f
    float sB = sigmoidf_(odd ? aB : 2.0f * aB);
    float vB = odd ? sB : (2.0f * sB - 1.0f);       // o or tanh(g)

    // two independent pair-exchanges: even lane receives f and o
    float f_n = __shfl_xor(vA, 1);
    float o_n = __shfl_xor(vB, 1);

    // cell update on even lanes: c = f*c + i*g ; h = o * tanh(c)
    c_reg = f_n * c_reg + vA * vB;
    float tc = 2.0f * sigmoidf_(2.0f * c_reg) - 1.0f;
    float h = o_n * tc;
    if (active && !odd) hw[k] = (_Float16)h;

    lds_barrier_();   // h_t visible; next step writes the OTHER buffer
  }

  // S even -> final h (t = S-1, odd) is in hb1
  if (tid < 3) {
    float acc = cls_b[tid];
    const float* cw = cls_W + tid * (HID + 3);
    #pragma unroll
    for (int j = 0; j < HID; ++j) acc += cw[j] * (float)hb1[grp][j];
    #pragma unroll
    for (int k2 = 0; k2 < 3; ++k2) acc += cw[HID + k2] * sent[b * 3 + k2];
    out[b * 3 + tid] = acc;
  }
}

extern "C" void kernel_launch(void* const* d_in, const int* in_sizes, int n_in,
                              void* d_out, int out_size, void* d_ws, size_t ws_size,
                              hipStream_t stream) {
  const int*   input_ids = (const int*)d_in[0];
  const float* mask      = (const float*)d_in[1];
  const float* sent      = (const float*)d_in[2];
  const float* hs        = (const float*)d_in[3];
  const float* logits    = (const float*)d_in[4];
  const float* W_ih      = (const float*)d_in[5];
  const float* W_hh      = (const float*)d_in[6];
  const float* b_ih      = (const float*)d_in[7];
  const float* b_hh      = (const float*)d_in[8];
  const float* cls_W     = (const float*)d_in[9];
  const float* cls_b     = (const float*)d_in[10];
  float* out = (float*)d_out;

  float* surp  = (float*)d_ws;            // M_TOT floats
  float* xproj = surp + M_TOT;            // M_TOT*400 floats

  surprisal_kernel<<<M_TOT, 256, 0, stream>>>(logits, input_ids, mask, surp);
  xproj_kernel<<<dim3(M_TOT / BM, (G4 + BN - 1) / BN), 256, 0, stream>>>(
      hs, surp, W_ih, b_ih, b_hh, xproj);
  lstm_kernel<<<B / 2, 512, 0, stream>>>(xproj, W_hh, sent, cls_W, cls_b, out);
}

// Round 10
// 1693.856 us; speedup vs baseline: 1.1588x; 1.1588x over previous
//
#include <hip/hip_runtime.h>
#include <hip/hip_bf16.h>
#include <math.h>

#define B 4
#define S 2048
#define H 768
#define V 32000
#define HID 100
#define G4 400   // 4*HID
#define M_TOT (B*S)
#define PD 2     // xproj prefetch depth (steps)

typedef _Float16 half2_t __attribute__((ext_vector_type(2)));
typedef _Float16 half8_t __attribute__((ext_vector_type(8)));
typedef int int4_t __attribute__((ext_vector_type(4)));

__device__ __forceinline__ float fdot2_(half2_t a, half2_t b, float c) {
#if __has_builtin(__builtin_amdgcn_fdot2)
  return __builtin_amdgcn_fdot2(a, b, c, false);
#else
  return c + (float)a[0] * (float)b[0] + (float)a[1] * (float)b[1];
#endif
}

__device__ __forceinline__ float sigmoidf_(float x) {
  return 1.0f / (1.0f + __expf(-x));
}

// Raw workgroup barrier: orders LDS (lgkmcnt drain) but does NOT drain vmcnt,
// so global prefetch loads stay in flight across steps.
__device__ __forceinline__ void lds_barrier_() {
  asm volatile("s_waitcnt lgkmcnt(0)" ::: "memory");
  __builtin_amdgcn_s_barrier();
  asm volatile("" ::: "memory");
}

// ---------------- Kernel 1: surprisal (online softmax + gather) --------------
__global__ __launch_bounds__(256) void surprisal_kernel(
    const float* __restrict__ logits, const int* __restrict__ ids,
    const float* __restrict__ mask, float* __restrict__ surp) {
  int row = blockIdx.x;
  const float* x = logits + (size_t)row * V;
  int tid = threadIdx.x;
  float m = -INFINITY, s = 0.0f;
  const float4* x4 = (const float4*)x;
  for (int i = tid; i < V / 4; i += 256) {
    float4 v = x4[i];
    float mv = fmaxf(fmaxf(v.x, v.y), fmaxf(v.z, v.w));
    if (mv > m) { s *= __expf(m - mv); m = mv; }
    s += __expf(v.x - m) + __expf(v.y - m) + __expf(v.z - m) + __expf(v.w - m);
  }
  #pragma unroll
  for (int off = 32; off > 0; off >>= 1) {
    float mo = __shfl_xor(m, off);
    float so = __shfl_xor(s, off);
    float mn = fmaxf(m, mo);
    s = s * __expf(m - mn) + so * __expf(mo - mn);
    m = mn;
  }
  __shared__ float sm[4], ss[4];
  int wid = tid >> 6, lane = tid & 63;
  if (lane == 0) { sm[wid] = m; ss[wid] = s; }
  __syncthreads();
  if (tid == 0) {
    float M = sm[0], Ssum = ss[0];
    #pragma unroll
    for (int w = 1; w < 4; ++w) {
      float mo = sm[w], so = ss[w];
      float mn = fmaxf(M, mo);
      Ssum = Ssum * __expf(M - mn) + so * __expf(mo - mn);
      M = mn;
    }
    float xid = x[ids[row]];
    surp[row] = (M + __logf(Ssum) - xid) * 1.4426950408889634f * mask[row];
  }
}

// ---------------- Kernel 2: x_proj (PERMUTED: col 4*unit + bitrev2(gate)) ----
// gate g in {i=0,f=1,g=2,o=3} -> slot {0,2,1,3}; so thread q of the LSTM
// (even q: unit q/2 gates (i,g); odd q: gates (f,o)) loads one float2 at 2q.
#define BM 64
#define BN 64
#define BK 32

__global__ __launch_bounds__(256) void xproj_kernel(
    const float* __restrict__ A,     // hidden_states [M,768]
    const float* __restrict__ surp,  // [M]
    const float* __restrict__ W,     // W_ih [400,769]
    const float* __restrict__ b_ih, const float* __restrict__ b_hh,
    float* __restrict__ xproj) {     // [M,400] permuted
  __shared__ float As[BK][BM];
  __shared__ float Bs[BK][BN];
  int tid = threadIdx.x;
  int m0 = blockIdx.x * BM;
  int n0 = blockIdx.y * BN;
  int tx = tid & 15, ty = tid >> 4;
  float acc[4][4] = {};
  for (int k0 = 0; k0 < H; k0 += BK) {
    #pragma unroll
    for (int l = 0; l < 2; ++l) {
      int idx = tid + l * 256;        // 0..511
      int row = idx >> 3;
      int kq = idx & 7;
      float4 v = *(const float4*)&A[(size_t)(m0 + row) * H + k0 + kq * 4];
      As[kq * 4 + 0][row] = v.x;
      As[kq * 4 + 1][row] = v.y;
      As[kq * 4 + 2][row] = v.z;
      As[kq * 4 + 3][row] = v.w;
    }
    #pragma unroll
    for (int l = 0; l < 8; ++l) {
      int idx = tid + l * 256;        // 0..2047
      int n = idx >> 5;
      int kk = idx & 31;
      int gn = n0 + n;
      Bs[kk][n] = (gn < G4) ? W[(size_t)gn * (H + 1) + k0 + kk] : 0.0f;
    }
    __syncthreads();
    #pragma unroll
    for (int k = 0; k < BK; ++k) {
      float4 a = *(const float4*)&As[k][ty * 4];
      float4 bq = *(const float4*)&Bs[k][tx * 4];
      float av[4] = {a.x, a.y, a.z, a.w};
      float bv[4] = {bq.x, bq.y, bq.z, bq.w};
      #pragma unroll
      for (int i = 0; i < 4; ++i)
        #pragma unroll
        for (int j = 0; j < 4; ++j)
          acc[i][j] += av[i] * bv[j];
    }
    __syncthreads();
  }
  #pragma unroll
  for (int i = 0; i < 4; ++i) {
    int gm = m0 + ty * 4 + i;
    float sv = surp[gm];
    #pragma unroll
    for (int j = 0; j < 4; ++j) {
      int gn = n0 + tx * 4 + j;   // gate-row index r = g*100 + k
      if (gn < G4) {
        float val = acc[i][j] + sv * W[(size_t)gn * (H + 1) + H] + b_ih[gn] + b_hh[gn];
        int g = gn / HID, k = gn % HID;
        int pn = 4 * k + (((g & 1) << 1) | (g >> 1));   // bitrev2(g)
        xproj[(size_t)gm * G4 + pn] = val;
      }
    }
  }
}

// ---------------- Kernel 3: LSTM scan + classifier ---------------------------
// Round-8 pair structure (best known: 1051 us) + PAIRED h-READS:
//   thread q<200 owns two gate rows of unit q/2 (even q -> (i,g), odd -> (f,o)).
//   h chunks (8 f16 = 16B) are read in PAIRS: even lane reads chunk 2m, odd
//   lane chunk 2m+1 in ONE ds_read_b128 (2 distinct addrs, conflict-free),
//   then exchanged via 4x shfl_xor(1) (DPP, VALU pipe). 13 LDS reads/wave ->
//   7, cutting DS-pipe delivery (each wave-read costs ~12cyc of RF-write BW
//   regardless of uniformity) from ~624 to ~336 cyc/step per CU. Weights are
//   stored parity-permuted at init so the hot loop stays statically indexed.
//   One raw barrier/step, double-buffered h, PD=2 coalesced float2 prefetch.
__global__ __launch_bounds__(256, 1) void lstm_kernel(
    const float* __restrict__ xproj,  // [B,S,400] permuted cols
    const float* __restrict__ W_hh,   // [400,100]
    const float* __restrict__ sent,   // [B,3]
    const float* __restrict__ cls_W,  // [3,103]
    const float* __restrict__ cls_b,  // [3]
    float* __restrict__ out) {        // [B,3]
  int b = blockIdx.x;
  int tid = threadIdx.x;
  __shared__ __align__(16) _Float16 hb0[104];
  __shared__ __align__(16) _Float16 hb1[104];

  bool active = tid < 200;
  int q = active ? tid : 199;          // clamp for uniform control flow
  int k = q >> 1;
  bool odd = (q & 1) != 0;
  int p = tid & 1;                     // lane parity (for paired reads)
  int rA = odd ? (HID + k) : k;                  // f : i
  int rB = odd ? (3 * HID + k) : (2 * HID + k);  // o : g

  // Weights, parity-permuted: pair m, slot s=0 -> chunk 2m+p (own read),
  // slot s=1 -> chunk 2m+1-p (neighbor's chunk via shfl). Chunk c covers h
  // elements [8c, 8c+8) as 4 half2. Tail chunk 12: elements 96..99 only.
  half2_t wA[6][2][4], wB[6][2][4], wtA[2], wtB[2];
  {
    const float* pA = W_hh + (size_t)rA * HID;
    const float* pB = W_hh + (size_t)rB * HID;
    #pragma unroll
    for (int m = 0; m < 6; ++m) {
      #pragma unroll
      for (int s = 0; s < 2; ++s) {
        int c = 2 * m + (s == 0 ? p : 1 - p);
        #pragma unroll
        for (int e = 0; e < 4; ++e) {
          wA[m][s][e] = half2_t{(_Float16)pA[8 * c + 2 * e], (_Float16)pA[8 * c + 2 * e + 1]};
          wB[m][s][e] = half2_t{(_Float16)pB[8 * c + 2 * e], (_Float16)pB[8 * c + 2 * e + 1]};
        }
      }
    }
    #pragma unroll
    for (int e = 0; e < 2; ++e) {
      wtA[e] = half2_t{(_Float16)pA[96 + 2 * e], (_Float16)pA[96 + 2 * e + 1]};
      wtB[e] = half2_t{(_Float16)pB[96 + 2 * e], (_Float16)pB[96 + 2 * e + 1]};
    }
  }

  float c_reg = 0.0f;
  if (tid < 104) { hb0[tid] = (_Float16)0; hb1[tid] = (_Float16)0; }
  __syncthreads();

  const float* xp = xproj + (size_t)b * S * G4;
  float2 xr[PD];
  #pragma unroll
  for (int d = 0; d < PD; ++d)
    xr[d] = ((const float2*)(xp + (size_t)d * G4))[q];

  #pragma unroll 2
  for (int t = 0; t < S; ++t) {
    int slot = t & (PD - 1);                       // static under unroll 2
    const _Float16* hr = (t & 1) ? hb0 : hb1;
    _Float16* hw = (t & 1) ? hb1 : hb0;

    float2 xv = xr[slot];
    // refill ring slot early (independent; stays in flight across barriers)
    {
      int tp = (t + PD < S) ? (t + PD) : (S - 1);
      xr[slot] = ((const float2*)(xp + (size_t)tp * G4))[q];
    }

    float a0 = 0.f, a1 = 0.f, b0 = 0.f, b1 = 0.f;
    #pragma unroll
    for (int m = 0; m < 6; ++m) {
      // one paired read: even lane gets chunk 2m, odd lane chunk 2m+1
      half8_t R = *(const half8_t*)(hr + (2 * m + p) * 8);
      int4_t Ri = __builtin_bit_cast(int4_t, R);
      int4_t Oi;
      Oi[0] = __shfl_xor(Ri[0], 1);
      Oi[1] = __shfl_xor(Ri[1], 1);
      Oi[2] = __shfl_xor(Ri[2], 1);
      Oi[3] = __shfl_xor(Ri[3], 1);
      half8_t O = __builtin_bit_cast(half8_t, Oi);
      // slot 0: own chunk (2m+p); slot 1: neighbor chunk (2m+1-p)
      half2_t r0 = {R[0], R[1]}, r1 = {R[2], R[3]}, r2 = {R[4], R[5]}, r3 = {R[6], R[7]};
      a0 = fdot2_(wA[m][0][0], r0, a0);
      b0 = fdot2_(wB[m][0][0], r0, b0);
      a1 = fdot2_(wA[m][0][1], r1, a1);
      b1 = fdot2_(wB[m][0][1], r1, b1);
      a0 = fdot2_(wA[m][0][2], r2, a0);
      b0 = fdot2_(wB[m][0][2], r2, b0);
      a1 = fdot2_(wA[m][0][3], r3, a1);
      b1 = fdot2_(wB[m][0][3], r3, b1);
      half2_t o0 = {O[0], O[1]}, o1 = {O[2], O[3]}, o2 = {O[4], O[5]}, o3 = {O[6], O[7]};
      a0 = fdot2_(wA[m][1][0], o0, a0);
      b0 = fdot2_(wB[m][1][0], o0, b0);
      a1 = fdot2_(wA[m][1][1], o1, a1);
      b1 = fdot2_(wB[m][1][1], o1, b1);
      a0 = fdot2_(wA[m][1][2], o2, a0);
      b0 = fdot2_(wB[m][1][2], o2, b0);
      a1 = fdot2_(wA[m][1][3], o3, a1);
      b1 = fdot2_(wB[m][1][3], o3, b1);
    }
    {
      // tail chunk 12 (h[96..99]): uniform read, 4 real half2 dots
      half8_t T = *(const half8_t*)(hr + 96);
      half2_t t0 = {T[0], T[1]}, t1 = {T[2], T[3]};
      a0 = fdot2_(wtA[0], t0, a0);
      b0 = fdot2_(wtB[0], t0, b0);
      a1 = fdot2_(wtA[1], t1, a1);
      b1 = fdot2_(wtB[1], t1, b1);
    }
    float aA = a0 + a1 + xv.x;   // even: i_pre ; odd: f_pre
    float aB = b0 + b1 + xv.y;   // even: g_pre ; odd: o_pre

    // local activations (uniform instruction stream, per-lane selects):
    float vA = sigmoidf_(aA);                       // i or f
    float sB = sigmoidf_(odd ? aB : 2.0f * aB);
    float vB = odd ? sB : (2.0f * sB - 1.0f);       // o or tanh(g)

    // two independent pair-exchanges: even lane receives f and o
    float f_n = __shfl_xor(vA, 1);
    float o_n = __shfl_xor(vB, 1);

    // cell update on even lanes: c = f*c + i*g ; h = o * tanh(c)
    c_reg = f_n * c_reg + vA * vB;
    float tc = 2.0f * sigmoidf_(2.0f * c_reg) - 1.0f;
    float h = o_n * tc;
    if (active && !odd) hw[k] = (_Float16)h;

    lds_barrier_();   // h_t visible; next step writes the OTHER buffer
  }

  // S even -> final h (t = S-1, odd) is in hb1
  if (tid < 3) {
    float acc = cls_b[tid];
    const float* cw = cls_W + tid * (HID + 3);
    #pragma unroll
    for (int j = 0; j < HID; ++j) acc += cw[j] * (float)hb1[j];
    #pragma unroll
    for (int k2 = 0; k2 < 3; ++k2) acc += cw[HID + k2] * sent[b * 3 + k2];
    out[b * 3 + tid] = acc;
  }
}

extern "C" void kernel_launch(void* const* d_in, const int* in_sizes, int n_in,
                              void* d_out, int out_size, void* d_ws, size_t ws_size,
                              hipStream_t stream) {
  const int*   input_ids = (const int*)d_in[0];
  const float* mask      = (const float*)d_in[1];
  const float* sent      = (const float*)d_in[2];
  const float* hs        = (const float*)d_in[3];
  const float* logits    = (const float*)d_in[4];
  const float* W_ih      = (const float*)d_in[5];
  const float* W_hh      = (const float*)d_in[6];
  const float* b_ih      = (const float*)d_in[7];
  const float* b_hh      = (const float*)d_in[8];
  const float* cls_W     = (const float*)d_in[9];
  const float* cls_b     = (const float*)d_in[10];
  float* out = (float*)d_out;

  float* surp  = (float*)d_ws;            // M_TOT floats
  float* xproj = surp + M_TOT;            // M_TOT*400 floats

  surprisal_kernel<<<M_TOT, 256, 0, stream>>>(logits, input_ids, mask, surp);
  xproj_kernel<<<dim3(M_TOT / BM, (G4 + BN - 1) / BN), 256, 0, stream>>>(
      hs, surp, W_ih, b_ih, b_hh, xproj);
  lstm_kernel<<<B, 256, 0, stream>>>(xproj, W_hh, sent, cls_W, cls_b, out);
}